// Round 9
// baseline (356.704 us; speedup 1.0000x reference)
//
#include <hip/hip_runtime.h>
#include <hip/hip_fp16.h>
#include <stdint.h>

#define TOKENS 4096
#define HDIM   2048
#define IDIM   5632
#define BM 128
#define BN 128
#define BK 64

#define G1_NP  11264
#define G1_KSB (G1_NP * 64)    // halves per K-tile panel of Bt (gate/up)

typedef _Float16 f16x8  __attribute__((ext_vector_type(8)));
typedef float    f32x4  __attribute__((ext_vector_type(4)));
typedef float    f32x16 __attribute__((ext_vector_type(16)));

// ---------- fp4 decode helpers (verified rounds 1-8) ----------
__device__ __forceinline__ uint32_t dec2(uint32_t z, uint32_t s2u) {
    uint32_t sgn = (z << 12) & 0x80008000u;
    uint32_t h   = ((z << 9) & 0x0E000E00u) | sgn;
    __half2 hv = __builtin_bit_cast(__half2, h);
    __half2 sv = __builtin_bit_cast(__half2, s2u);
    __half2 r  = __hmul2(hv, sv);
    return __builtin_bit_cast(uint32_t, r);
}
__device__ __forceinline__ int4 dec8(uint32_t w, uint32_t s2u) {
    int4 d;
    d.x = (int)dec2( w        & 0x000F000Fu, s2u);
    d.y = (int)dec2((w >> 4)  & 0x000F000Fu, s2u);
    d.z = (int)dec2((w >> 8)  & 0x000F000Fu, s2u);
    d.w = (int)dec2((w >> 12) & 0x000F000Fu, s2u);
    return d;
}
__device__ __forceinline__ uint32_t scale_s2u(float sc) {
    uint16_t hs = __builtin_bit_cast(uint16_t, __float2half(sc * 16384.0f));
    return (uint32_t)hs * 0x00010001u;
}
__device__ __forceinline__ uint32_t packh(float lo, float hi) {
    __half2 h2 = __halves2half2(__float2half(lo), __float2half(hi));
    return __builtin_bit_cast(uint32_t, h2);
}
__device__ __forceinline__ void gl_lds16(const void* g, void* l) {
    __builtin_amdgcn_global_load_lds(
        (const __attribute__((address_space(1))) uint32_t*)g,
        (__attribute__((address_space(3))) uint32_t*)l, 16, 0, 0);
}

// ---------- hidden fp32 -> f16, sigma k-order within each 8-group ----------
__global__ __launch_bounds__(256) void convert_hidden(
    const float* __restrict__ src, __half* __restrict__ dst)
{
    int idx = blockIdx.x * 256 + threadIdx.x;   // one 8-group per thread
    const float4* s = (const float4*)src + (size_t)idx * 2;
    float4 a = s[0], b = s[1];                  // a = x0..x3, b = x4..x7
    int4 v;
    v.x = (int)packh(a.x, b.x);                 // pos 0,1 = x0,x4
    v.y = (int)packh(a.y, b.y);
    v.z = (int)packh(a.z, b.z);
    v.w = (int)packh(a.w, b.w);
    *((int4*)dst + idx) = v;
}

// ---------- dequant W_gu v7 -> f16 panels Bt[32][11264][64].
// np interleave: np = pair*64 + sel*32 + w32  (gate/up alternate by 32 cols).
// Thread <-> (np, j): wave stores one CONTIGUOUS 1 KB burst; wave reads
// 8 rows x 32 consecutive cols (full 128 B line per block). ----------
__global__ __launch_bounds__(256) void dequant_wgu7(
    const uint32_t* __restrict__ W, const float* __restrict__ S,
    __half* __restrict__ Bt)
{
    const int kt = blockIdx.y;                       // 0..31
    const int t  = threadIdx.x;
    const int np = blockIdx.x * 32 + (t >> 3);       // interleaved row
    const int j  = t & 7;                            // k-word in tile
    const int sc = (np >> 6) * 32 + (np & 31) + (((np >> 5) & 1) ? IDIM : 0);
    uint32_t s2u = scale_s2u(S[(size_t)(kt >> 1) * (2 * IDIM) + sc]);
    uint32_t w   = W[(size_t)(kt * 8 + j) * (2 * IDIM) + sc];
    int4 d = dec8(w, s2u);
    *(int4*)(Bt + (size_t)kt * G1_KSB + (size_t)np * 64 + j * 8) = d;
}

// ---------- GEMM1: r5 proven staging structure, 32x32x16 MFMA.
// 128x128 tile, 256 thr, 4 waves (64x64 each = 2x2 frags of 32x32),
// single-buffer 32 KB LDS, gl_lds staging with per-lane source swizzle. ----------
__global__ __launch_bounds__(256, 4) void gemm1_s32(
    const __half* __restrict__ A, const __half* __restrict__ Bt,
    __half* __restrict__ act)
{
    __shared__ __half Alds[BM * 64];   // 16 KB
    __shared__ __half Blds[BN * 64];   // 16 KB
    const int tid  = threadIdx.x;
    const int lane = tid & 63;
    const int wid  = tid >> 6;
    const int wm = wid >> 1, wn = wid & 1;
    const int m0 = blockIdx.y * BM;
    const int n0 = blockIdx.x * BN;

    f32x16 acc[2][2];
    #pragma unroll
    for (int i = 0; i < 2; ++i)
        #pragma unroll
        for (int j = 0; j < 2; ++j)
            #pragma unroll
            for (int e = 0; e < 16; ++e) acc[i][j][e] = 0.f;

    const __half* srcA[4];
    const __half* srcB[4];
    #pragma unroll
    for (int i = 0; i < 4; ++i) {
        int u = i * 256 + tid, row = u >> 3, s = u & 7, sl = s ^ (row & 7);
        srcA[i] = A  + (size_t)(m0 + row) * HDIM + sl * 8;
        srcB[i] = Bt + (size_t)(n0 + row) * 64 + sl * 8;
    }

    const int l31 = lane & 31;
    const int h   = lane >> 5;
    const int rA0 = wm * 64 + l31;
    const int rB0 = wn * 64 + l31;

    for (int kt = 0; kt < HDIM / 64; ++kt) {
        #pragma unroll
        for (int i = 0; i < 4; ++i) {
            int u = i * 256 + tid;
            gl_lds16(srcA[i], (char*)Alds + u * 16);
            gl_lds16(srcB[i], (char*)Blds + u * 16);
            srcA[i] += 64;
            srcB[i] += G1_KSB;
        }
        __syncthreads();
        #pragma unroll
        for (int kk = 0; kk < 4; ++kk) {
            const int s8 = kk * 2 + h;
            f16x8 a0, a1, b0, b1;
            { int r = rA0;      a0 = *(const f16x8*)&Alds[r * 64 + ((s8 ^ (r & 7)) << 3)]; }
            { int r = rA0 + 32; a1 = *(const f16x8*)&Alds[r * 64 + ((s8 ^ (r & 7)) << 3)]; }
            { int r = rB0;      b0 = *(const f16x8*)&Blds[r * 64 + ((s8 ^ (r & 7)) << 3)]; }
            { int r = rB0 + 32; b1 = *(const f16x8*)&Blds[r * 64 + ((s8 ^ (r & 7)) << 3)]; }
            acc[0][0] = __builtin_amdgcn_mfma_f32_32x32x16_f16(a0, b0, acc[0][0], 0, 0, 0);
            acc[0][1] = __builtin_amdgcn_mfma_f32_32x32x16_f16(a0, b1, acc[0][1], 0, 0, 0);
            acc[1][0] = __builtin_amdgcn_mfma_f32_32x32x16_f16(a1, b0, acc[1][0], 0, 0, 0);
            acc[1][1] = __builtin_amdgcn_mfma_f32_32x32x16_f16(a1, b1, acc[1][1], 0, 0, 0);
        }
        __syncthreads();
    }

    // epilogue: silu(gate)*up -> act. nf=0 gate frag, nf=1 up frag.
    // C/D: col=lane&31, row=(reg&3)+8*(reg>>2)+4*(lane>>5). sigma col slot.
    const int gcol = ((n0 + wn * 64) >> 6) * 32 + l31;
    const int colstore = (gcol & ~7) | (((gcol & 3) << 1) | ((gcol >> 2) & 1));
    #pragma unroll
    for (int mi = 0; mi < 2; ++mi) {
        #pragma unroll
        for (int reg = 0; reg < 16; ++reg) {
            int m = m0 + wm * 64 + mi * 32 + (reg & 3) + 8 * (reg >> 2) + 4 * h;
            float gv = acc[mi][0][reg];
            float uv = acc[mi][1][reg];
            float sig = 1.0f / (1.0f + __expf(-gv));
            act[(size_t)m * IDIM + colstore] = __float2half(gv * sig * uv);
        }
    }
}

// ---------- round-1 fused-decode GEMM1 (fallback if ws too small) ----------
__global__ __launch_bounds__(256, 2) void gemm1_silu(
    const __half* __restrict__ A, const uint32_t* __restrict__ W,
    const float* __restrict__ S, __half* __restrict__ act)
{
    __shared__ __half Alds[BM * BK];
    __shared__ __half Blds[2][BN * BK];
    const int tid  = threadIdx.x;
    const int lane = tid & 63;
    const int wid  = tid >> 6;
    const int wm = wid >> 1, wn = wid & 1;
    const int m0 = blockIdx.y * BM;
    const int c0 = blockIdx.x * BN;

    f32x4 accg[4][4], accu[4][4];
    #pragma unroll
    for (int i = 0; i < 4; ++i)
        #pragma unroll
        for (int j = 0; j < 4; ++j) {
            accg[i][j] = f32x4{0.f, 0.f, 0.f, 0.f};
            accu[i][j] = f32x4{0.f, 0.f, 0.f, 0.f};
        }

    const int c = tid & 127;
    const int rbase = (tid >> 7) * 4;

    for (int kt = 0; kt < HDIM / BK; ++kt) {
        const int k0 = kt * BK;
        #pragma unroll
        for (int i = 0; i < 4; ++i) {
            int u = tid + i * 256;
            int row = u >> 3, kb = u & 7;
            int4 v = *(const int4*)(A + (size_t)(m0 + row) * HDIM + k0 + kb * 8);
            *(int4*)((char*)Alds + row * 128 + ((kb ^ (row & 7)) << 4)) = v;
        }
        const int g = k0 >> 7;
        #pragma unroll
        for (int p = 0; p < 2; ++p) {
            const int ncol = (p ? IDIM : 0) + c0 + c;
            uint32_t s2u = scale_s2u(S[(size_t)g * (2 * IDIM) + ncol]);
            #pragma unroll
            for (int i = 0; i < 4; ++i) {
                int rl = rbase + i;
                uint32_t w = W[(size_t)(kt * 8 + rl) * (2 * IDIM) + ncol];
                int4 d = dec8(w, s2u);
                *(int4*)((char*)&Blds[p][0] + c * 128 + ((rl ^ (c & 7)) << 4)) = d;
            }
        }
        __syncthreads();
        #pragma unroll
        for (int ks = 0; ks < 2; ++ks) {
            f16x8 af[4], bg[4], bu[4];
            const int kb = ks * 4 + (lane >> 4);
            #pragma unroll
            for (int mi = 0; mi < 4; ++mi) {
                int m = wm * 64 + mi * 16 + (lane & 15);
                af[mi] = *(const f16x8*)((const char*)Alds + m * 128 + ((kb ^ (m & 7)) << 4));
            }
            #pragma unroll
            for (int ni = 0; ni < 4; ++ni) {
                int n = wn * 64 + ni * 16 + (lane & 15);
                bg[ni] = *(const f16x8*)((const char*)&Blds[0][0] + n * 128 + ((kb ^ (n & 7)) << 4));
                bu[ni] = *(const f16x8*)((const char*)&Blds[1][0] + n * 128 + ((kb ^ (n & 7)) << 4));
            }
            #pragma unroll
            for (int mi = 0; mi < 4; ++mi)
                #pragma unroll
                for (int ni = 0; ni < 4; ++ni) {
                    accg[mi][ni] = __builtin_amdgcn_mfma_f32_16x16x32_f16(af[mi], bg[ni], accg[mi][ni], 0, 0, 0);
                    accu[mi][ni] = __builtin_amdgcn_mfma_f32_16x16x32_f16(af[mi], bu[ni], accu[mi][ni], 0, 0, 0);
                }
        }
        __syncthreads();
    }
    #pragma unroll
    for (int mi = 0; mi < 4; ++mi) {
        #pragma unroll
        for (int ni = 0; ni < 4; ++ni) {
            int nlog = c0 + wn * 64 + ni * 16 + (lane & 15);
            int ncol = (nlog & ~7) | (((nlog & 3) << 1) | ((nlog >> 2) & 1));
            #pragma unroll
            for (int r = 0; r < 4; ++r) {
                int m = m0 + wm * 64 + mi * 16 + (lane >> 4) * 4 + r;
                float gv = accg[mi][ni][r];
                float uv = accu[mi][ni][r];
                float sig = 1.0f / (1.0f + __expf(-gv));
                act[(size_t)m * IDIM + ncol] = __float2half(gv * sig * uv);
            }
        }
    }
}

// ---------- GEMM2 (fused decode, 32x32x16): out = moe + act @ deq(Wd) ----------
__global__ __launch_bounds__(256, 2) void gemm2_add32(
    const __half* __restrict__ A, const uint32_t* __restrict__ W,
    const float* __restrict__ S, const float* __restrict__ moe,
    float* __restrict__ out)
{
    __shared__ __half Alds[BM * BK];
    __shared__ __half Blds[BN * BK];
    const int tid  = threadIdx.x;
    const int lane = tid & 63;
    const int wid  = tid >> 6;
    const int wm = wid >> 1, wn = wid & 1;
    const int m0 = blockIdx.y * BM;
    const int n0 = blockIdx.x * BN;

    f32x16 acc[2][2];
    #pragma unroll
    for (int i = 0; i < 2; ++i)
        #pragma unroll
        for (int j = 0; j < 2; ++j)
            #pragma unroll
            for (int e = 0; e < 16; ++e) acc[i][j][e] = 0.f;

    const int c = tid & 127;
    const int rbase = (tid >> 7) * 4;
    const int l31 = lane & 31;
    const int h   = lane >> 5;
    const int rA0 = wm * 64 + l31;
    const int rB0 = wn * 64 + l31;

    for (int kt = 0; kt < IDIM / BK; ++kt) {
        const int k0 = kt * BK;
        #pragma unroll
        for (int i = 0; i < 4; ++i) {
            int u = tid + i * 256;
            int row = u >> 3, kb = u & 7;
            int4 v = *(const int4*)(A + (size_t)(m0 + row) * IDIM + k0 + kb * 8);
            *(int4*)((char*)Alds + row * 128 + ((kb ^ (row & 7)) << 4)) = v;
        }
        {
            const int g = k0 >> 7;
            const int ncol = n0 + c;
            uint32_t s2u = scale_s2u(S[(size_t)g * HDIM + ncol]);
            #pragma unroll
            for (int i = 0; i < 4; ++i) {
                int rl = rbase + i;
                uint32_t w = W[(size_t)(kt * 8 + rl) * HDIM + ncol];
                int4 d = dec8(w, s2u);
                *(int4*)((char*)Blds + c * 128 + ((rl ^ (c & 7)) << 4)) = d;
            }
        }
        __syncthreads();
        #pragma unroll
        for (int kk = 0; kk < 4; ++kk) {
            const int s8 = kk * 2 + h;
            f16x8 a0, a1, b0, b1;
            { int r = rA0;      a0 = *(const f16x8*)((const char*)Alds + r * 128 + ((s8 ^ (r & 7)) << 4)); }
            { int r = rA0 + 32; a1 = *(const f16x8*)((const char*)Alds + r * 128 + ((s8 ^ (r & 7)) << 4)); }
            { int r = rB0;      b0 = *(const f16x8*)((const char*)Blds + r * 128 + ((s8 ^ (r & 7)) << 4)); }
            { int r = rB0 + 32; b1 = *(const f16x8*)((const char*)Blds + r * 128 + ((s8 ^ (r & 7)) << 4)); }
            acc[0][0] = __builtin_amdgcn_mfma_f32_32x32x16_f16(a0, b0, acc[0][0], 0, 0, 0);
            acc[0][1] = __builtin_amdgcn_mfma_f32_32x32x16_f16(a0, b1, acc[0][1], 0, 0, 0);
            acc[1][0] = __builtin_amdgcn_mfma_f32_32x32x16_f16(a1, b0, acc[1][0], 0, 0, 0);
            acc[1][1] = __builtin_amdgcn_mfma_f32_32x32x16_f16(a1, b1, acc[1][1], 0, 0, 0);
        }
        __syncthreads();
    }
    #pragma unroll
    for (int mi = 0; mi < 2; ++mi)
        #pragma unroll
        for (int nf = 0; nf < 2; ++nf)
            #pragma unroll
            for (int reg = 0; reg < 16; ++reg) {
                int m = m0 + wm * 64 + mi * 32 + (reg & 3) + 8 * (reg >> 2) + 4 * h;
                int n = n0 + wn * 64 + nf * 32 + l31;
                out[(size_t)m * HDIM + n] = moe[(size_t)m * HDIM + n] + acc[mi][nf][reg];
            }
}

extern "C" void kernel_launch(void* const* d_in, const int* in_sizes, int n_in,
                              void* d_out, int out_size, void* d_ws, size_t ws_size,
                              hipStream_t stream) {
    const float*    hidden = (const float*)d_in[0];
    const float*    moe    = (const float*)d_in[1];
    const uint32_t* wgu    = (const uint32_t*)d_in[2];
    const float*    sgu    = (const float*)d_in[3];
    const uint32_t* wd     = (const uint32_t*)d_in[4];
    const float*    sd     = (const float*)d_in[5];
    float* out = (float*)d_out;

    const size_t sz_hidden = (size_t)TOKENS * HDIM * 2;      // 16.78 MB
    const size_t sz_act    = (size_t)TOKENS * IDIM * 2;      // 46.14 MB
    const size_t sz_wgu16  = (size_t)HDIM * 2 * IDIM * 2;    // 46.14 MB

    __half* hidden_f16 = (__half*)d_ws;
    __half* act        = (__half*)((char*)d_ws + sz_hidden);
    __half* wgu16      = (__half*)((char*)d_ws + sz_hidden + sz_act);

    const size_t need_g1 = sz_hidden + sz_act + sz_wgu16;    // 109 MB (available r5-r8)

    convert_hidden<<<dim3(TOKENS * HDIM / 8 / 256), dim3(256), 0, stream>>>(hidden, hidden_f16);

    if (ws_size >= need_g1) {
        dequant_wgu7<<<dim3(G1_NP / 32, 32), dim3(256), 0, stream>>>(wgu, sgu, wgu16);
        gemm1_s32<<<dim3(G1_NP / BN, TOKENS / BM), dim3(256), 0, stream>>>(hidden_f16, wgu16, act);
    } else {
        gemm1_silu<<<dim3(IDIM / BN, TOKENS / BM), dim3(256), 0, stream>>>(hidden_f16, wgu, sgu, act);
    }

    gemm2_add32<<<dim3(HDIM / BN, TOKENS / BM), dim3(256), 0, stream>>>(act, wd, sd, moe, out);
}

// Round 10
// 356.319 us; speedup vs baseline: 1.0011x; 1.0011x over previous
//
#include <hip/hip_runtime.h>
#include <hip/hip_fp16.h>
#include <stdint.h>

#define TOKENS 4096
#define HDIM   2048
#define IDIM   5632
#define BM 128
#define BN 128
#define BK 64

#define G1_NP  11264
#define G1_KSB (G1_NP * 64)    // halves per K-tile panel of Bt (gate/up)

typedef _Float16 f16x8 __attribute__((ext_vector_type(8)));
typedef float    f32x4 __attribute__((ext_vector_type(4)));

// ---------- fp4 decode helpers (verified rounds 1-9) ----------
__device__ __forceinline__ uint32_t dec2(uint32_t z, uint32_t s2u) {
    uint32_t sgn = (z << 12) & 0x80008000u;
    uint32_t h   = ((z << 9) & 0x0E000E00u) | sgn;
    __half2 hv = __builtin_bit_cast(__half2, h);
    __half2 sv = __builtin_bit_cast(__half2, s2u);
    __half2 r  = __hmul2(hv, sv);
    return __builtin_bit_cast(uint32_t, r);
}
__device__ __forceinline__ int4 dec8(uint32_t w, uint32_t s2u) {
    int4 d;
    d.x = (int)dec2( w        & 0x000F000Fu, s2u);
    d.y = (int)dec2((w >> 4)  & 0x000F000Fu, s2u);
    d.z = (int)dec2((w >> 8)  & 0x000F000Fu, s2u);
    d.w = (int)dec2((w >> 12) & 0x000F000Fu, s2u);
    return d;
}
__device__ __forceinline__ uint32_t scale_s2u(float sc) {
    uint16_t hs = __builtin_bit_cast(uint16_t, __float2half(sc * 16384.0f));
    return (uint32_t)hs * 0x00010001u;
}
__device__ __forceinline__ uint32_t packh(float lo, float hi) {
    __half2 h2 = __halves2half2(__float2half(lo), __float2half(hi));
    return __builtin_bit_cast(uint32_t, h2);
}
__device__ __forceinline__ void gl_lds16(const void* g, void* l) {
    __builtin_amdgcn_global_load_lds(
        (const __attribute__((address_space(1))) uint32_t*)g,
        (__attribute__((address_space(3))) uint32_t*)l, 16, 0, 0);
}

// ---------- hidden fp32 -> f16, sigma k-order within each 8-group ----------
__global__ __launch_bounds__(256) void convert_hidden(
    const float* __restrict__ src, __half* __restrict__ dst)
{
    int idx = blockIdx.x * 256 + threadIdx.x;   // one 8-group per thread
    const float4* s = (const float4*)src + (size_t)idx * 2;
    float4 a = s[0], b = s[1];                  // a = x0..x3, b = x4..x7
    int4 v;
    v.x = (int)packh(a.x, b.x);                 // pos 0,1 = x0,x4
    v.y = (int)packh(a.y, b.y);
    v.z = (int)packh(a.z, b.z);
    v.w = (int)packh(a.w, b.w);
    *((int4*)dst + idx) = v;
}

// ---------- dequant W_gu v7 -> f16 panels Bt[32][11264][64].
// np interleave: np = pair*64 + sel*32 + w32 (gate/up alternate by 32 cols).
// Thread <-> (np, j): wave stores one CONTIGUOUS 1 KB burst; wave reads
// 8 rows x 32 consecutive cols (full 128 B lines). ----------
__global__ __launch_bounds__(256) void dequant_wgu7(
    const uint32_t* __restrict__ W, const float* __restrict__ S,
    __half* __restrict__ Bt)
{
    const int kt = blockIdx.y;                       // 0..31
    const int t  = threadIdx.x;
    const int np = blockIdx.x * 32 + (t >> 3);       // interleaved row
    const int j  = t & 7;                            // k-word in tile
    const int sc = (np >> 6) * 32 + (np & 31) + (((np >> 5) & 1) ? IDIM : 0);
    uint32_t s2u = scale_s2u(S[(size_t)(kt >> 1) * (2 * IDIM) + sc]);
    uint32_t w   = W[(size_t)(kt * 8 + j) * (2 * IDIM) + sc];
    int4 d = dec8(w, s2u);
    *(int4*)(Bt + (size_t)kt * G1_KSB + (size_t)np * 64 + j * 8) = d;
}

// ---------- GEMM1: proven r5 structure (16x16 MFMA, 53% MfmaUtil, 0 conflicts),
// + bijective XCD swizzle (each XCD owns 4 contiguous M-panels -> A refetch 8x -> 1x).
// Epilogue adapted to the 32-col gate/up interleave: ni=0,1 gate, ni=2,3 up. ----------
__global__ __launch_bounds__(256, 4) void gemm1_s(
    const __half* __restrict__ A, const __half* __restrict__ Bt,
    __half* __restrict__ act)
{
    __shared__ __half Alds[BM * 64];   // 16 KB
    __shared__ __half Blds[BN * 64];   // 16 KB
    const int tid  = threadIdx.x;
    const int lane = tid & 63;
    const int wid  = tid >> 6;
    const int wm = wid >> 1, wn = wid & 1;

    // XCD swizzle: 2816 blocks, by-major flatten; XCD k owns nn in [k*352,(k+1)*352)
    // = 4 full M-panels x 88 N. Bijective (2816 % 8 == 0).
    const int o  = blockIdx.x;
    const int nn = (o & 7) * 352 + (o >> 3);
    const int by = nn / 88, bx = nn % 88;
    const int m0 = by * BM;
    const int n0 = bx * BN;

    f32x4 acc[4][4];
    #pragma unroll
    for (int i = 0; i < 4; ++i)
        #pragma unroll
        for (int j = 0; j < 4; ++j) acc[i][j] = f32x4{0.f, 0.f, 0.f, 0.f};

    const __half* srcA[4];
    const __half* srcB[4];
    #pragma unroll
    for (int i = 0; i < 4; ++i) {
        int u = i * 256 + tid, row = u >> 3, s = u & 7, sl = s ^ (row & 7);
        srcA[i] = A  + (size_t)(m0 + row) * HDIM + sl * 8;
        srcB[i] = Bt + (size_t)(n0 + row) * 64 + sl * 8;
    }

    for (int kt = 0; kt < HDIM / 64; ++kt) {
        #pragma unroll
        for (int i = 0; i < 4; ++i) {
            int u = i * 256 + tid;
            gl_lds16(srcA[i], (char*)Alds + u * 16);
            gl_lds16(srcB[i], (char*)Blds + u * 16);
            srcA[i] += 64;
            srcB[i] += G1_KSB;
        }
        __syncthreads();
        #pragma unroll
        for (int ks = 0; ks < 2; ++ks) {
            f16x8 af[4], bf[4];
            const int kb = ks * 4 + (lane >> 4);
            #pragma unroll
            for (int mi = 0; mi < 4; ++mi) {
                int r = wm * 64 + mi * 16 + (lane & 15);
                af[mi] = *(const f16x8*)&Alds[r * 64 + ((kb ^ (r & 7)) << 3)];
            }
            #pragma unroll
            for (int ni = 0; ni < 4; ++ni) {
                int r = wn * 64 + ni * 16 + (lane & 15);
                bf[ni] = *(const f16x8*)&Blds[r * 64 + ((kb ^ (r & 7)) << 3)];
            }
            #pragma unroll
            for (int mi = 0; mi < 4; ++mi)
                #pragma unroll
                for (int ni = 0; ni < 4; ++ni)
                    acc[mi][ni] = __builtin_amdgcn_mfma_f32_16x16x32_f16(af[mi], bf[ni], acc[mi][ni], 0, 0, 0);
        }
        __syncthreads();
    }

    // epilogue: 32-col interleave -> wave's B rows [wn*64, wn*64+64) are one
    // pair group: ni=0,1 gate cols (q*16), ni=2,3 up cols. sigma col slot.
    const int pairbase = ((n0 + wn * 64) >> 6) * 32;
    #pragma unroll
    for (int mi = 0; mi < 4; ++mi) {
        #pragma unroll
        for (int q = 0; q < 2; ++q) {
            int gcol = pairbase + q * 16 + (lane & 15);
            int colstore = (gcol & ~7) | (((gcol & 3) << 1) | ((gcol >> 2) & 1));
            #pragma unroll
            for (int r = 0; r < 4; ++r) {
                int m = m0 + wm * 64 + mi * 16 + (lane >> 4) * 4 + r;
                float gv = acc[mi][q][r];
                float uv = acc[mi][q + 2][r];
                float sig = 1.0f / (1.0f + __expf(-gv));
                act[(size_t)m * IDIM + colstore] = __float2half(gv * sig * uv);
            }
        }
    }
}

// ---------- round-1 fused-decode GEMM1 (fallback if ws too small) ----------
__global__ __launch_bounds__(256, 2) void gemm1_silu(
    const __half* __restrict__ A, const uint32_t* __restrict__ W,
    const float* __restrict__ S, __half* __restrict__ act)
{
    __shared__ __half Alds[BM * BK];
    __shared__ __half Blds[2][BN * BK];
    const int tid  = threadIdx.x;
    const int lane = tid & 63;
    const int wid  = tid >> 6;
    const int wm = wid >> 1, wn = wid & 1;
    const int m0 = blockIdx.y * BM;
    const int c0 = blockIdx.x * BN;

    f32x4 accg[4][4], accu[4][4];
    #pragma unroll
    for (int i = 0; i < 4; ++i)
        #pragma unroll
        for (int j = 0; j < 4; ++j) {
            accg[i][j] = f32x4{0.f, 0.f, 0.f, 0.f};
            accu[i][j] = f32x4{0.f, 0.f, 0.f, 0.f};
        }

    const int c = tid & 127;
    const int rbase = (tid >> 7) * 4;

    for (int kt = 0; kt < HDIM / BK; ++kt) {
        const int k0 = kt * BK;
        #pragma unroll
        for (int i = 0; i < 4; ++i) {
            int u = tid + i * 256;
            int row = u >> 3, kb = u & 7;
            int4 v = *(const int4*)(A + (size_t)(m0 + row) * HDIM + k0 + kb * 8);
            *(int4*)((char*)Alds + row * 128 + ((kb ^ (row & 7)) << 4)) = v;
        }
        const int g = k0 >> 7;
        #pragma unroll
        for (int p = 0; p < 2; ++p) {
            const int ncol = (p ? IDIM : 0) + c0 + c;
            uint32_t s2u = scale_s2u(S[(size_t)g * (2 * IDIM) + ncol]);
            #pragma unroll
            for (int i = 0; i < 4; ++i) {
                int rl = rbase + i;
                uint32_t w = W[(size_t)(kt * 8 + rl) * (2 * IDIM) + ncol];
                int4 d = dec8(w, s2u);
                *(int4*)((char*)&Blds[p][0] + c * 128 + ((rl ^ (c & 7)) << 4)) = d;
            }
        }
        __syncthreads();
        #pragma unroll
        for (int ks = 0; ks < 2; ++ks) {
            f16x8 af[4], bg[4], bu[4];
            const int kb = ks * 4 + (lane >> 4);
            #pragma unroll
            for (int mi = 0; mi < 4; ++mi) {
                int m = wm * 64 + mi * 16 + (lane & 15);
                af[mi] = *(const f16x8*)((const char*)Alds + m * 128 + ((kb ^ (m & 7)) << 4));
            }
            #pragma unroll
            for (int ni = 0; ni < 4; ++ni) {
                int n = wn * 64 + ni * 16 + (lane & 15);
                bg[ni] = *(const f16x8*)((const char*)&Blds[0][0] + n * 128 + ((kb ^ (n & 7)) << 4));
                bu[ni] = *(const f16x8*)((const char*)&Blds[1][0] + n * 128 + ((kb ^ (n & 7)) << 4));
            }
            #pragma unroll
            for (int mi = 0; mi < 4; ++mi)
                #pragma unroll
                for (int ni = 0; ni < 4; ++ni) {
                    accg[mi][ni] = __builtin_amdgcn_mfma_f32_16x16x32_f16(af[mi], bg[ni], accg[mi][ni], 0, 0, 0);
                    accu[mi][ni] = __builtin_amdgcn_mfma_f32_16x16x32_f16(af[mi], bu[ni], accu[mi][ni], 0, 0, 0);
                }
        }
        __syncthreads();
    }
    #pragma unroll
    for (int mi = 0; mi < 4; ++mi) {
        #pragma unroll
        for (int ni = 0; ni < 4; ++ni) {
            int nlog = c0 + wn * 64 + ni * 16 + (lane & 15);
            int ncol = (nlog & ~7) | (((nlog & 3) << 1) | ((nlog >> 2) & 1));
            #pragma unroll
            for (int r = 0; r < 4; ++r) {
                int m = m0 + wm * 64 + mi * 16 + (lane >> 4) * 4 + r;
                float gv = accg[mi][ni][r];
                float uv = accu[mi][ni][r];
                float sig = 1.0f / (1.0f + __expf(-gv));
                act[(size_t)m * IDIM + ncol] = __float2half(gv * sig * uv);
            }
        }
    }
}

// ---------- GEMM2 (fused decode, proven ~90 us) + XCD swizzle ----------
__global__ __launch_bounds__(256, 2) void gemm2_add(
    const __half* __restrict__ A, const uint32_t* __restrict__ W,
    const float* __restrict__ S, const float* __restrict__ moe,
    float* __restrict__ out)
{
    __shared__ __half Alds[BM * BK];
    __shared__ __half Blds[BN * BK];
    const int tid  = threadIdx.x;
    const int lane = tid & 63;
    const int wid  = tid >> 6;
    const int wm = wid >> 1, wn = wid & 1;

    // XCD swizzle: 512 blocks, by-major flatten; XCD k owns 4 M-panels.
    const int o  = blockIdx.x;
    const int nn = (o & 7) * 64 + (o >> 3);
    const int by = nn >> 4, bx = nn & 15;
    const int m0 = by * BM;
    const int n0 = bx * BN;

    f32x4 acc[4][4];
    #pragma unroll
    for (int i = 0; i < 4; ++i)
        #pragma unroll
        for (int j = 0; j < 4; ++j) acc[i][j] = f32x4{0.f, 0.f, 0.f, 0.f};

    const int c = tid & 127;
    const int rbase = (tid >> 7) * 4;

    for (int kt = 0; kt < IDIM / BK; ++kt) {
        const int k0 = kt * BK;
        #pragma unroll
        for (int i = 0; i < 4; ++i) {
            int u = tid + i * 256;
            int row = u >> 3, kb = u & 7;
            int4 v = *(const int4*)(A + (size_t)(m0 + row) * IDIM + k0 + kb * 8);
            *(int4*)((char*)Alds + row * 128 + ((kb ^ (row & 7)) << 4)) = v;
        }
        {
            const int g = k0 >> 7;
            const int ncol = n0 + c;
            uint32_t s2u = scale_s2u(S[(size_t)g * HDIM + ncol]);
            #pragma unroll
            for (int i = 0; i < 4; ++i) {
                int rl = rbase + i;
                uint32_t w = W[(size_t)(kt * 8 + rl) * HDIM + ncol];
                int4 d = dec8(w, s2u);
                *(int4*)((char*)Blds + c * 128 + ((rl ^ (c & 7)) << 4)) = d;
            }
        }
        __syncthreads();
        #pragma unroll
        for (int ks = 0; ks < 2; ++ks) {
            f16x8 af[4], bf[4];
            const int kb = ks * 4 + (lane >> 4);
            #pragma unroll
            for (int mi = 0; mi < 4; ++mi) {
                int m = wm * 64 + mi * 16 + (lane & 15);
                af[mi] = *(const f16x8*)((const char*)Alds + m * 128 + ((kb ^ (m & 7)) << 4));
            }
            #pragma unroll
            for (int ni = 0; ni < 4; ++ni) {
                int n = wn * 64 + ni * 16 + (lane & 15);
                bf[ni] = *(const f16x8*)((const char*)Blds + n * 128 + ((kb ^ (n & 7)) << 4));
            }
            #pragma unroll
            for (int mi = 0; mi < 4; ++mi)
                #pragma unroll
                for (int ni = 0; ni < 4; ++ni)
                    acc[mi][ni] = __builtin_amdgcn_mfma_f32_16x16x32_f16(af[mi], bf[ni], acc[mi][ni], 0, 0, 0);
        }
        __syncthreads();
    }
    #pragma unroll
    for (int mi = 0; mi < 4; ++mi) {
        #pragma unroll
        for (int ni = 0; ni < 4; ++ni) {
            int n = n0 + wn * 64 + ni * 16 + (lane & 15);
            #pragma unroll
            for (int r = 0; r < 4; ++r) {
                int m = m0 + wm * 64 + mi * 16 + (lane >> 4) * 4 + r;
                out[(size_t)m * HDIM + n] = moe[(size_t)m * HDIM + n] + acc[mi][ni][r];
            }
        }
    }
}

extern "C" void kernel_launch(void* const* d_in, const int* in_sizes, int n_in,
                              void* d_out, int out_size, void* d_ws, size_t ws_size,
                              hipStream_t stream) {
    const float*    hidden = (const float*)d_in[0];
    const float*    moe    = (const float*)d_in[1];
    const uint32_t* wgu    = (const uint32_t*)d_in[2];
    const float*    sgu    = (const float*)d_in[3];
    const uint32_t* wd     = (const uint32_t*)d_in[4];
    const float*    sd     = (const float*)d_in[5];
    float* out = (float*)d_out;

    const size_t sz_hidden = (size_t)TOKENS * HDIM * 2;      // 16.78 MB
    const size_t sz_act    = (size_t)TOKENS * IDIM * 2;      // 46.14 MB
    const size_t sz_wgu16  = (size_t)HDIM * 2 * IDIM * 2;    // 46.14 MB

    __half* hidden_f16 = (__half*)d_ws;
    __half* act        = (__half*)((char*)d_ws + sz_hidden);
    __half* wgu16      = (__half*)((char*)d_ws + sz_hidden + sz_act);

    const size_t need_g1 = sz_hidden + sz_act + sz_wgu16;    // 109 MB (available r5-r9)

    convert_hidden<<<dim3(TOKENS * HDIM / 8 / 256), dim3(256), 0, stream>>>(hidden, hidden_f16);

    if (ws_size >= need_g1) {
        dequant_wgu7<<<dim3(G1_NP / 32, 32), dim3(256), 0, stream>>>(wgu, sgu, wgu16);
        gemm1_s<<<dim3((G1_NP / BN) * (TOKENS / BM)), dim3(256), 0, stream>>>(hidden_f16, wgu16, act);
    } else {
        gemm1_silu<<<dim3(IDIM / BN, TOKENS / BM), dim3(256), 0, stream>>>(hidden_f16, wgu, sgu, act);
    }

    gemm2_add<<<dim3((HDIM / BN) * (TOKENS / BM)), dim3(256), 0, stream>>>(act, wd, sd, moe, out);
}

// Round 11
// 326.037 us; speedup vs baseline: 1.0941x; 1.0929x over previous
//
#include <hip/hip_runtime.h>
#include <hip/hip_fp16.h>
#include <stdint.h>

#define TOKENS 4096
#define HDIM   2048
#define IDIM   5632
#define BM 128
#define BN 128
#define BK 64

#define G1_NP  11264
#define G1_KSB (G1_NP * 64)    // halves per K-tile panel of Bt (gate/up)

typedef _Float16 f16x8 __attribute__((ext_vector_type(8)));
typedef float    f32x4 __attribute__((ext_vector_type(4)));

// ---------- fp4 decode helpers (verified rounds 1-10) ----------
__device__ __forceinline__ uint32_t dec2(uint32_t z, uint32_t s2u) {
    uint32_t sgn = (z << 12) & 0x80008000u;
    uint32_t h   = ((z << 9) & 0x0E000E00u) | sgn;
    __half2 hv = __builtin_bit_cast(__half2, h);
    __half2 sv = __builtin_bit_cast(__half2, s2u);
    __half2 r  = __hmul2(hv, sv);
    return __builtin_bit_cast(uint32_t, r);
}
__device__ __forceinline__ int4 dec8(uint32_t w, uint32_t s2u) {
    int4 d;
    d.x = (int)dec2( w        & 0x000F000Fu, s2u);
    d.y = (int)dec2((w >> 4)  & 0x000F000Fu, s2u);
    d.z = (int)dec2((w >> 8)  & 0x000F000Fu, s2u);
    d.w = (int)dec2((w >> 12) & 0x000F000Fu, s2u);
    return d;
}
__device__ __forceinline__ uint32_t scale_s2u(float sc) {
    uint16_t hs = __builtin_bit_cast(uint16_t, __float2half(sc * 16384.0f));
    return (uint32_t)hs * 0x00010001u;
}
__device__ __forceinline__ uint32_t packh(float lo, float hi) {
    __half2 h2 = __halves2half2(__float2half(lo), __float2half(hi));
    return __builtin_bit_cast(uint32_t, h2);
}
__device__ __forceinline__ void gl_lds16(const void* g, void* l) {
    __builtin_amdgcn_global_load_lds(
        (const __attribute__((address_space(1))) uint32_t*)g,
        (__attribute__((address_space(3))) uint32_t*)l, 16, 0, 0);
}

// ---------- hidden fp32 -> f16, sigma k-order within each 8-group ----------
__global__ __launch_bounds__(256) void convert_hidden(
    const float* __restrict__ src, __half* __restrict__ dst)
{
    int idx = blockIdx.x * 256 + threadIdx.x;   // one 8-group per thread
    const float4* s = (const float4*)src + (size_t)idx * 2;
    float4 a = s[0], b = s[1];                  // a = x0..x3, b = x4..x7
    int4 v;
    v.x = (int)packh(a.x, b.x);                 // pos 0,1 = x0,x4
    v.y = (int)packh(a.y, b.y);
    v.z = (int)packh(a.z, b.z);
    v.w = (int)packh(a.w, b.w);
    *((int4*)dst + idx) = v;
}

// ---------- dequant W_gu v7 -> f16 panels Bt[32][11264][64].
// np interleave: np = pair*64 + sel*32 + w32 (gate/up alternate by 32 cols).
// Thread <-> (np, j): wave stores one CONTIGUOUS 1 KB burst; block reads
// full 128 B lines. ----------
__global__ __launch_bounds__(256) void dequant_wgu7(
    const uint32_t* __restrict__ W, const float* __restrict__ S,
    __half* __restrict__ Bt)
{
    const int kt = blockIdx.y;                       // 0..31
    const int t  = threadIdx.x;
    const int np = blockIdx.x * 32 + (t >> 3);       // interleaved row
    const int j  = t & 7;                            // k-word in tile
    const int sc = (np >> 6) * 32 + (np & 31) + (((np >> 5) & 1) ? IDIM : 0);
    uint32_t s2u = scale_s2u(S[(size_t)(kt >> 1) * (2 * IDIM) + sc]);
    uint32_t w   = W[(size_t)(kt * 8 + j) * (2 * IDIM) + sc];
    int4 d = dec8(w, s2u);
    *(int4*)(Bt + (size_t)kt * G1_KSB + (size_t)np * 64 + j * 8) = d;
}

// ---------- GEMM1: proven r5 structure (16x16 MFMA, 53% MfmaUtil, 0 conflicts),
// 2D grid (bx-fastest launch order = best measured L2 locality), 5 blocks/CU.
// LDS-read byte offsets hoisted to registers (loop-invariant across kt).
// Epilogue: 32-col gate/up interleave (ni=0,1 gate / ni=2,3 up). ----------
__global__ __launch_bounds__(256, 4) void gemm1_s(
    const __half* __restrict__ A, const __half* __restrict__ Bt,
    __half* __restrict__ act)
{
    __shared__ __half Alds[BM * 64];   // 16 KB
    __shared__ __half Blds[BN * 64];   // 16 KB
    const int tid  = threadIdx.x;
    const int lane = tid & 63;
    const int wid  = tid >> 6;
    const int wm = wid >> 1, wn = wid & 1;
    const int m0 = blockIdx.y * BM;
    const int n0 = blockIdx.x * BN;

    f32x4 acc[4][4];
    #pragma unroll
    for (int i = 0; i < 4; ++i)
        #pragma unroll
        for (int j = 0; j < 4; ++j) acc[i][j] = f32x4{0.f, 0.f, 0.f, 0.f};

    const __half* srcA[4];
    const __half* srcB[4];
    #pragma unroll
    for (int i = 0; i < 4; ++i) {
        int u = i * 256 + tid, row = u >> 3, s = u & 7, sl = s ^ (row & 7);
        srcA[i] = A  + (size_t)(m0 + row) * HDIM + sl * 8;
        srcB[i] = Bt + (size_t)(n0 + row) * 64 + sl * 8;
    }

    // hoisted LDS-read byte offsets (invariant across kt)
    int aoff[4][2], boff[4][2];
    #pragma unroll
    for (int f = 0; f < 4; ++f)
        #pragma unroll
        for (int ks = 0; ks < 2; ++ks) {
            int kb = ks * 4 + (lane >> 4);
            int ra = wm * 64 + f * 16 + (lane & 15);
            int rb = wn * 64 + f * 16 + (lane & 15);
            aoff[f][ks] = ra * 128 + ((kb ^ (ra & 7)) << 4);
            boff[f][ks] = rb * 128 + ((kb ^ (rb & 7)) << 4);
        }

    for (int kt = 0; kt < HDIM / 64; ++kt) {
        #pragma unroll
        for (int i = 0; i < 4; ++i) {
            int u = i * 256 + tid;
            gl_lds16(srcA[i], (char*)Alds + u * 16);
            gl_lds16(srcB[i], (char*)Blds + u * 16);
            srcA[i] += 64;
            srcB[i] += G1_KSB;
        }
        __syncthreads();
        #pragma unroll
        for (int ks = 0; ks < 2; ++ks) {
            f16x8 af[4], bf[4];
            #pragma unroll
            for (int f = 0; f < 4; ++f) {
                af[f] = *(const f16x8*)((const char*)Alds + aoff[f][ks]);
                bf[f] = *(const f16x8*)((const char*)Blds + boff[f][ks]);
            }
            #pragma unroll
            for (int mi = 0; mi < 4; ++mi)
                #pragma unroll
                for (int ni = 0; ni < 4; ++ni)
                    acc[mi][ni] = __builtin_amdgcn_mfma_f32_16x16x32_f16(af[mi], bf[ni], acc[mi][ni], 0, 0, 0);
        }
        __syncthreads();
    }

    // epilogue: 32-col interleave -> ni=0,1 gate cols, ni=2,3 up cols. sigma slot.
    const int pairbase = ((n0 + wn * 64) >> 6) * 32;
    #pragma unroll
    for (int mi = 0; mi < 4; ++mi) {
        #pragma unroll
        for (int q = 0; q < 2; ++q) {
            int gcol = pairbase + q * 16 + (lane & 15);
            int colstore = (gcol & ~7) | (((gcol & 3) << 1) | ((gcol >> 2) & 1));
            #pragma unroll
            for (int r = 0; r < 4; ++r) {
                int m = m0 + wm * 64 + mi * 16 + (lane >> 4) * 4 + r;
                float gv = acc[mi][q][r];
                float uv = acc[mi][q + 2][r];
                float sig = 1.0f / (1.0f + __expf(-gv));
                act[(size_t)m * IDIM + colstore] = __float2half(gv * sig * uv);
            }
        }
    }
}

// ---------- round-1 fused-decode GEMM1 (fallback if ws too small) ----------
__global__ __launch_bounds__(256, 2) void gemm1_silu(
    const __half* __restrict__ A, const uint32_t* __restrict__ W,
    const float* __restrict__ S, __half* __restrict__ act)
{
    __shared__ __half Alds[BM * BK];
    __shared__ __half Blds[2][BN * BK];
    const int tid  = threadIdx.x;
    const int lane = tid & 63;
    const int wid  = tid >> 6;
    const int wm = wid >> 1, wn = wid & 1;
    const int m0 = blockIdx.y * BM;
    const int c0 = blockIdx.x * BN;

    f32x4 accg[4][4], accu[4][4];
    #pragma unroll
    for (int i = 0; i < 4; ++i)
        #pragma unroll
        for (int j = 0; j < 4; ++j) {
            accg[i][j] = f32x4{0.f, 0.f, 0.f, 0.f};
            accu[i][j] = f32x4{0.f, 0.f, 0.f, 0.f};
        }

    const int c = tid & 127;
    const int rbase = (tid >> 7) * 4;

    for (int kt = 0; kt < HDIM / BK; ++kt) {
        const int k0 = kt * BK;
        #pragma unroll
        for (int i = 0; i < 4; ++i) {
            int u = tid + i * 256;
            int row = u >> 3, kb = u & 7;
            int4 v = *(const int4*)(A + (size_t)(m0 + row) * HDIM + k0 + kb * 8);
            *(int4*)((char*)Alds + row * 128 + ((kb ^ (row & 7)) << 4)) = v;
        }
        const int g = k0 >> 7;
        #pragma unroll
        for (int p = 0; p < 2; ++p) {
            const int ncol = (p ? IDIM : 0) + c0 + c;
            uint32_t s2u = scale_s2u(S[(size_t)g * (2 * IDIM) + ncol]);
            #pragma unroll
            for (int i = 0; i < 4; ++i) {
                int rl = rbase + i;
                uint32_t w = W[(size_t)(kt * 8 + rl) * (2 * IDIM) + ncol];
                int4 d = dec8(w, s2u);
                *(int4*)((char*)&Blds[p][0] + c * 128 + ((rl ^ (c & 7)) << 4)) = d;
            }
        }
        __syncthreads();
        #pragma unroll
        for (int ks = 0; ks < 2; ++ks) {
            f16x8 af[4], bg[4], bu[4];
            const int kb = ks * 4 + (lane >> 4);
            #pragma unroll
            for (int mi = 0; mi < 4; ++mi) {
                int m = wm * 64 + mi * 16 + (lane & 15);
                af[mi] = *(const f16x8*)((const char*)Alds + m * 128 + ((kb ^ (m & 7)) << 4));
            }
            #pragma unroll
            for (int ni = 0; ni < 4; ++ni) {
                int n = wn * 64 + ni * 16 + (lane & 15);
                bg[ni] = *(const f16x8*)((const char*)&Blds[0][0] + n * 128 + ((kb ^ (n & 7)) << 4));
                bu[ni] = *(const f16x8*)((const char*)&Blds[1][0] + n * 128 + ((kb ^ (n & 7)) << 4));
            }
            #pragma unroll
            for (int mi = 0; mi < 4; ++mi)
                #pragma unroll
                for (int ni = 0; ni < 4; ++ni) {
                    accg[mi][ni] = __builtin_amdgcn_mfma_f32_16x16x32_f16(af[mi], bg[ni], accg[mi][ni], 0, 0, 0);
                    accu[mi][ni] = __builtin_amdgcn_mfma_f32_16x16x32_f16(af[mi], bu[ni], accu[mi][ni], 0, 0, 0);
                }
        }
        __syncthreads();
    }
    #pragma unroll
    for (int mi = 0; mi < 4; ++mi) {
        #pragma unroll
        for (int ni = 0; ni < 4; ++ni) {
            int nlog = c0 + wn * 64 + ni * 16 + (lane & 15);
            int ncol = (nlog & ~7) | (((nlog & 3) << 1) | ((nlog >> 2) & 1));
            #pragma unroll
            for (int r = 0; r < 4; ++r) {
                int m = m0 + wm * 64 + mi * 16 + (lane >> 4) * 4 + r;
                float gv = accg[mi][ni][r];
                float uv = accu[mi][ni][r];
                float sig = 1.0f / (1.0f + __expf(-gv));
                act[(size_t)m * IDIM + ncol] = __float2half(gv * sig * uv);
            }
        }
    }
}

// ---------- GEMM2 (fused decode, proven ~90 us, 2D grid) ----------
__global__ __launch_bounds__(256, 2) void gemm2_add(
    const __half* __restrict__ A, const uint32_t* __restrict__ W,
    const float* __restrict__ S, const float* __restrict__ moe,
    float* __restrict__ out)
{
    __shared__ __half Alds[BM * BK];
    __shared__ __half Blds[BN * BK];
    const int tid  = threadIdx.x;
    const int lane = tid & 63;
    const int wid  = tid >> 6;
    const int wm = wid >> 1, wn = wid & 1;
    const int m0 = blockIdx.y * BM;
    const int n0 = blockIdx.x * BN;

    f32x4 acc[4][4];
    #pragma unroll
    for (int i = 0; i < 4; ++i)
        #pragma unroll
        for (int j = 0; j < 4; ++j) acc[i][j] = f32x4{0.f, 0.f, 0.f, 0.f};

    const int c = tid & 127;
    const int rbase = (tid >> 7) * 4;

    // hoisted LDS-read byte offsets (invariant across kt)
    int aoff[4][2], boff[4][2];
    #pragma unroll
    for (int f = 0; f < 4; ++f)
        #pragma unroll
        for (int ks = 0; ks < 2; ++ks) {
            int kb = ks * 4 + (lane >> 4);
            int ra = wm * 64 + f * 16 + (lane & 15);
            int rb = wn * 64 + f * 16 + (lane & 15);
            aoff[f][ks] = ra * 128 + ((kb ^ (ra & 7)) << 4);
            boff[f][ks] = rb * 128 + ((kb ^ (rb & 7)) << 4);
        }

    for (int kt = 0; kt < IDIM / BK; ++kt) {
        const int k0 = kt * BK;
        #pragma unroll
        for (int i = 0; i < 4; ++i) {
            int u = tid + i * 256;
            int row = u >> 3, kb = u & 7;
            int4 v = *(const int4*)(A + (size_t)(m0 + row) * IDIM + k0 + kb * 8);
            *(int4*)((char*)Alds + row * 128 + ((kb ^ (row & 7)) << 4)) = v;
        }
        {
            const int g = k0 >> 7;
            const int ncol = n0 + c;
            uint32_t s2u = scale_s2u(S[(size_t)g * HDIM + ncol]);
            #pragma unroll
            for (int i = 0; i < 4; ++i) {
                int rl = rbase + i;
                uint32_t w = W[(size_t)(kt * 8 + rl) * HDIM + ncol];
                int4 d = dec8(w, s2u);
                *(int4*)((char*)Blds + c * 128 + ((rl ^ (c & 7)) << 4)) = d;
            }
        }
        __syncthreads();
        #pragma unroll
        for (int ks = 0; ks < 2; ++ks) {
            f16x8 af[4], bf[4];
            #pragma unroll
            for (int f = 0; f < 4; ++f) {
                af[f] = *(const f16x8*)((const char*)Alds + aoff[f][ks]);
                bf[f] = *(const f16x8*)((const char*)Blds + boff[f][ks]);
            }
            #pragma unroll
            for (int mi = 0; mi < 4; ++mi)
                #pragma unroll
                for (int ni = 0; ni < 4; ++ni)
                    acc[mi][ni] = __builtin_amdgcn_mfma_f32_16x16x32_f16(af[mi], bf[ni], acc[mi][ni], 0, 0, 0);
        }
        __syncthreads();
    }
    #pragma unroll
    for (int mi = 0; mi < 4; ++mi) {
        #pragma unroll
        for (int ni = 0; ni < 4; ++ni) {
            int n = n0 + wn * 64 + ni * 16 + (lane & 15);
            #pragma unroll
            for (int r = 0; r < 4; ++r) {
                int m = m0 + wm * 64 + mi * 16 + (lane >> 4) * 4 + r;
                out[(size_t)m * HDIM + n] = moe[(size_t)m * HDIM + n] + acc[mi][ni][r];
            }
        }
    }
}

extern "C" void kernel_launch(void* const* d_in, const int* in_sizes, int n_in,
                              void* d_out, int out_size, void* d_ws, size_t ws_size,
                              hipStream_t stream) {
    const float*    hidden = (const float*)d_in[0];
    const float*    moe    = (const float*)d_in[1];
    const uint32_t* wgu    = (const uint32_t*)d_in[2];
    const float*    sgu    = (const float*)d_in[3];
    const uint32_t* wd     = (const uint32_t*)d_in[4];
    const float*    sd     = (const float*)d_in[5];
    float* out = (float*)d_out;

    const size_t sz_hidden = (size_t)TOKENS * HDIM * 2;      // 16.78 MB
    const size_t sz_act    = (size_t)TOKENS * IDIM * 2;      // 46.14 MB
    const size_t sz_wgu16  = (size_t)HDIM * 2 * IDIM * 2;    // 46.14 MB

    __half* hidden_f16 = (__half*)d_ws;
    __half* act        = (__half*)((char*)d_ws + sz_hidden);
    __half* wgu16      = (__half*)((char*)d_ws + sz_hidden + sz_act);

    const size_t need_g1 = sz_hidden + sz_act + sz_wgu16;    // 109 MB (available r5-r10)

    convert_hidden<<<dim3(TOKENS * HDIM / 8 / 256), dim3(256), 0, stream>>>(hidden, hidden_f16);

    if (ws_size >= need_g1) {
        dequant_wgu7<<<dim3(G1_NP / 32, 32), dim3(256), 0, stream>>>(wgu, sgu, wgu16);
        gemm1_s<<<dim3(G1_NP / BN, TOKENS / BM), dim3(256), 0, stream>>>(hidden_f16, wgu16, act);
    } else {
        gemm1_silu<<<dim3(IDIM / BN, TOKENS / BM), dim3(256), 0, stream>>>(hidden_f16, wgu, sgu, act);
    }

    gemm2_add<<<dim3(HDIM / BN, TOKENS / BM), dim3(256), 0, stream>>>(act, wd, sd, moe, out);
}

// Round 12
// 321.575 us; speedup vs baseline: 1.1092x; 1.0139x over previous
//
#include <hip/hip_runtime.h>
#include <hip/hip_fp16.h>
#include <stdint.h>

#define TOKENS 4096
#define HDIM   2048
#define IDIM   5632
#define BM 128
#define BN 128
#define BK 64

#define G1_NP  11264
#define G1_KSB (G1_NP * 64)    // halves per K-tile panel of Bt (gate/up)

typedef _Float16 f16x8 __attribute__((ext_vector_type(8)));
typedef float    f32x4 __attribute__((ext_vector_type(4)));

// ---------- fp4 decode helpers (verified rounds 1-11) ----------
__device__ __forceinline__ uint32_t dec2(uint32_t z, uint32_t s2u) {
    uint32_t sgn = (z << 12) & 0x80008000u;
    uint32_t h   = ((z << 9) & 0x0E000E00u) | sgn;
    __half2 hv = __builtin_bit_cast(__half2, h);
    __half2 sv = __builtin_bit_cast(__half2, s2u);
    __half2 r  = __hmul2(hv, sv);
    return __builtin_bit_cast(uint32_t, r);
}
__device__ __forceinline__ int4 dec8(uint32_t w, uint32_t s2u) {
    int4 d;
    d.x = (int)dec2( w        & 0x000F000Fu, s2u);
    d.y = (int)dec2((w >> 4)  & 0x000F000Fu, s2u);
    d.z = (int)dec2((w >> 8)  & 0x000F000Fu, s2u);
    d.w = (int)dec2((w >> 12) & 0x000F000Fu, s2u);
    return d;
}
__device__ __forceinline__ uint32_t scale_s2u(float sc) {
    uint16_t hs = __builtin_bit_cast(uint16_t, __float2half(sc * 16384.0f));
    return (uint32_t)hs * 0x00010001u;
}
__device__ __forceinline__ uint32_t packh(float lo, float hi) {
    __half2 h2 = __halves2half2(__float2half(lo), __float2half(hi));
    return __builtin_bit_cast(uint32_t, h2);
}
__device__ __forceinline__ void gl_lds16(const void* g, void* l) {
    __builtin_amdgcn_global_load_lds(
        (const __attribute__((address_space(1))) uint32_t*)g,
        (__attribute__((address_space(3))) uint32_t*)l, 16, 0, 0);
}

// ---------- hidden fp32 -> f16, sigma k-order within each 8-group ----------
__global__ __launch_bounds__(256) void convert_hidden(
    const float* __restrict__ src, __half* __restrict__ dst)
{
    int idx = blockIdx.x * 256 + threadIdx.x;   // one 8-group per thread
    const float4* s = (const float4*)src + (size_t)idx * 2;
    float4 a = s[0], b = s[1];                  // a = x0..x3, b = x4..x7
    int4 v;
    v.x = (int)packh(a.x, b.x);                 // pos 0,1 = x0,x4
    v.y = (int)packh(a.y, b.y);
    v.z = (int)packh(a.z, b.z);
    v.w = (int)packh(a.w, b.w);
    *((int4*)dst + idx) = v;
}

// ---------- dequant W_gu v7 -> f16 panels Bt[32][11264][64].
// np interleave: np = pair*64 + sel*32 + w32 (gate/up alternate by 32 cols).
// Thread <-> (np, j): wave stores one CONTIGUOUS 1 KB burst. ----------
__global__ __launch_bounds__(256) void dequant_wgu7(
    const uint32_t* __restrict__ W, const float* __restrict__ S,
    __half* __restrict__ Bt)
{
    const int kt = blockIdx.y;                       // 0..31
    const int t  = threadIdx.x;
    const int np = blockIdx.x * 32 + (t >> 3);       // interleaved row
    const int j  = t & 7;                            // k-word in tile
    const int sc = (np >> 6) * 32 + (np & 31) + (((np >> 5) & 1) ? IDIM : 0);
    uint32_t s2u = scale_s2u(S[(size_t)(kt >> 1) * (2 * IDIM) + sc]);
    uint32_t w   = W[(size_t)(kt * 8 + j) * (2 * IDIM) + sc];
    int4 d = dec8(w, s2u);
    *(int4*)(Bt + (size_t)kt * G1_KSB + (size_t)np * 64 + j * 8) = d;
}

// ---------- GEMM1 v2: 256x256 tile, 8 waves (128x64 each), 4 quadrant-phases
// per K-tile, double-buffered 128 KB LDS, counted vmcnt(8) once per K-tile.
// vs r4: NO XCD swizzle, NO sched_barrier/lgkmcnt pinning (compiler schedules
// ds_read->MFMA waits), source-side chunk swizzle in staging pointers. ----------
__global__ __launch_bounds__(512, 1) void gemm1_8ph2(
    const __half* __restrict__ A, const __half* __restrict__ Bt,
    __half* __restrict__ act)
{
    __shared__ __half Al[2][256 * 64];   // 2 x 32 KB
    __shared__ __half Bl[2][256 * 64];   // 2 x 32 KB  (128 KB)
    const int tid  = threadIdx.x;
    const int lane = tid & 63;
    const int wid  = tid >> 6;
    const int wm   = wid >> 2;   // 0..1 : rows wm*128
    const int wn   = wid & 3;    // 0..3 : B rows wn*64

    const int m0 = blockIdx.y * 256;
    const int n0 = blockIdx.x * 256;

    // staging sources with per-chunk swizzle: chunk u -> row u>>3, slot (u&7)^(row&7)
    const __half* srcA[4];
    const __half* srcB[4];
    #pragma unroll
    for (int i = 0; i < 4; ++i) {
        int u = i * 512 + tid, row = u >> 3, s = u & 7, sl = s ^ (row & 7);
        srcA[i] = A  + (size_t)(m0 + row) * HDIM + sl * 8;
        srcB[i] = Bt + (size_t)(n0 + row) * 64 + sl * 8;
    }

    auto stageA = [&](int buf, int kt) {
        #pragma unroll
        for (int i = 0; i < 4; ++i)
            gl_lds16(srcA[i] + (size_t)kt * 64, (char*)&Al[buf][0] + (i * 512 + tid) * 16);
    };
    auto stageB = [&](int buf, int kt) {
        #pragma unroll
        for (int i = 0; i < 4; ++i)
            gl_lds16(srcB[i] + (size_t)kt * G1_KSB, (char*)&Bl[buf][0] + (i * 512 + tid) * 16);
    };

    f32x4 acc[8][4];
    #pragma unroll
    for (int i = 0; i < 8; ++i)
        #pragma unroll
        for (int j = 0; j < 4; ++j) acc[i][j] = f32x4{0.f, 0.f, 0.f, 0.f};

    const int rA0 = wm * 128 + (lane & 15);
    const int rB0 = wn * 64  + (lane & 15);
    const int kb0 = lane >> 4;

    // prologue: stage K0 (buf0), K1 (buf1); wait own K0 loads; barrier
    stageB(0, 0); stageA(0, 0);
    stageB(1, 1); stageA(1, 1);
    asm volatile("s_waitcnt vmcnt(8)" ::: "memory");
    asm volatile("s_barrier" ::: "memory");

    f16x8 a[4][2], b[4][2];
    for (int kt = 0; kt < 32; ++kt) {
        const int cur = kt & 1;
        const __half* Ac = &Al[cur][0];
        const __half* Bc = &Bl[cur][0];
        const bool st = kt < 30;

        // ---- P1: ds_read A(mi0-3) + B(ni0-1); MFMA Q1 ----
        #pragma unroll
        for (int mi = 0; mi < 4; ++mi)
            #pragma unroll
            for (int kk = 0; kk < 2; ++kk) {
                int r = rA0 + mi * 16;
                a[mi][kk] = *(const f16x8*)&Ac[r * 64 + (((kb0 + kk * 4) ^ (r & 7)) << 3)];
            }
        #pragma unroll
        for (int ni = 0; ni < 2; ++ni)
            #pragma unroll
            for (int kk = 0; kk < 2; ++kk) {
                int r = rB0 + ni * 16;
                b[ni][kk] = *(const f16x8*)&Bc[r * 64 + (((kb0 + kk * 4) ^ (r & 7)) << 3)];
            }
        asm volatile("s_barrier" ::: "memory");
        __builtin_amdgcn_s_setprio(1);
        #pragma unroll
        for (int mi = 0; mi < 4; ++mi)
            #pragma unroll
            for (int ni = 0; ni < 2; ++ni)
                #pragma unroll
                for (int kk = 0; kk < 2; ++kk)
                    acc[mi][ni] = __builtin_amdgcn_mfma_f32_16x16x32_f16(a[mi][kk], b[ni][kk], acc[mi][ni], 0, 0, 0);
        __builtin_amdgcn_s_setprio(0);
        asm volatile("s_barrier" ::: "memory");

        // ---- P2: ds_read B(ni2-3); MFMA Q2 ----
        #pragma unroll
        for (int ni = 2; ni < 4; ++ni)
            #pragma unroll
            for (int kk = 0; kk < 2; ++kk) {
                int r = rB0 + ni * 16;
                b[ni][kk] = *(const f16x8*)&Bc[r * 64 + (((kb0 + kk * 4) ^ (r & 7)) << 3)];
            }
        asm volatile("s_barrier" ::: "memory");
        __builtin_amdgcn_s_setprio(1);
        #pragma unroll
        for (int mi = 0; mi < 4; ++mi)
            #pragma unroll
            for (int ni = 2; ni < 4; ++ni)
                #pragma unroll
                for (int kk = 0; kk < 2; ++kk)
                    acc[mi][ni] = __builtin_amdgcn_mfma_f32_16x16x32_f16(a[mi][kk], b[ni][kk], acc[mi][ni], 0, 0, 0);
        __builtin_amdgcn_s_setprio(0);
        asm volatile("s_barrier" ::: "memory");

        // ---- P3: ds_read A(mi4-7); stage B(kt+2) [B LDS region now dead]; MFMA Q3 ----
        #pragma unroll
        for (int mi = 0; mi < 4; ++mi)
            #pragma unroll
            for (int kk = 0; kk < 2; ++kk) {
                int r = rA0 + (mi + 4) * 16;
                a[mi][kk] = *(const f16x8*)&Ac[r * 64 + (((kb0 + kk * 4) ^ (r & 7)) << 3)];
            }
        if (st) stageB(cur, kt + 2);
        asm volatile("s_barrier" ::: "memory");
        __builtin_amdgcn_s_setprio(1);
        #pragma unroll
        for (int mi = 0; mi < 4; ++mi)
            #pragma unroll
            for (int ni = 2; ni < 4; ++ni)
                #pragma unroll
                for (int kk = 0; kk < 2; ++kk)
                    acc[mi + 4][ni] = __builtin_amdgcn_mfma_f32_16x16x32_f16(a[mi][kk], b[ni][kk], acc[mi + 4][ni], 0, 0, 0);
        __builtin_amdgcn_s_setprio(0);
        asm volatile("s_barrier" ::: "memory");

        // ---- P4: stage A(kt+2) [A LDS region now dead]; MFMA Q4; vmcnt once ----
        if (st) stageA(cur, kt + 2);
        asm volatile("s_barrier" ::: "memory");
        __builtin_amdgcn_s_setprio(1);
        #pragma unroll
        for (int mi = 0; mi < 4; ++mi)
            #pragma unroll
            for (int ni = 0; ni < 2; ++ni)
                #pragma unroll
                for (int kk = 0; kk < 2; ++kk)
                    acc[mi + 4][ni] = __builtin_amdgcn_mfma_f32_16x16x32_f16(a[mi][kk], b[ni][kk], acc[mi + 4][ni], 0, 0, 0);
        __builtin_amdgcn_s_setprio(0);
        if (st) asm volatile("s_waitcnt vmcnt(8)" ::: "memory");
        else    asm volatile("s_waitcnt vmcnt(0)" ::: "memory");
        asm volatile("s_barrier" ::: "memory");
    }

    // epilogue: 32-col gate/up interleave -> ni=0,1 gate, ni=2,3 up; sigma slot
    const int pairbase = ((n0 + wn * 64) >> 6) * 32;
    #pragma unroll
    for (int mi = 0; mi < 8; ++mi) {
        #pragma unroll
        for (int q = 0; q < 2; ++q) {
            int gcol = pairbase + q * 16 + (lane & 15);
            int colstore = (gcol & ~7) | (((gcol & 3) << 1) | ((gcol >> 2) & 1));
            #pragma unroll
            for (int r = 0; r < 4; ++r) {
                int m = m0 + wm * 128 + mi * 16 + (lane >> 4) * 4 + r;
                float gv = acc[mi][q][r];
                float uv = acc[mi][q + 2][r];
                float sig = 1.0f / (1.0f + __expf(-gv));
                act[(size_t)m * IDIM + colstore] = __float2half(gv * sig * uv);
            }
        }
    }
}

// ---------- round-1 fused-decode GEMM1 (fallback if ws too small) ----------
__global__ __launch_bounds__(256, 2) void gemm1_silu(
    const __half* __restrict__ A, const uint32_t* __restrict__ W,
    const float* __restrict__ S, __half* __restrict__ act)
{
    __shared__ __half Alds[BM * BK];
    __shared__ __half Blds[2][BN * BK];
    const int tid  = threadIdx.x;
    const int lane = tid & 63;
    const int wid  = tid >> 6;
    const int wm = wid >> 1, wn = wid & 1;
    const int m0 = blockIdx.y * BM;
    const int c0 = blockIdx.x * BN;

    f32x4 accg[4][4], accu[4][4];
    #pragma unroll
    for (int i = 0; i < 4; ++i)
        #pragma unroll
        for (int j = 0; j < 4; ++j) {
            accg[i][j] = f32x4{0.f, 0.f, 0.f, 0.f};
            accu[i][j] = f32x4{0.f, 0.f, 0.f, 0.f};
        }

    const int c = tid & 127;
    const int rbase = (tid >> 7) * 4;

    for (int kt = 0; kt < HDIM / BK; ++kt) {
        const int k0 = kt * BK;
        #pragma unroll
        for (int i = 0; i < 4; ++i) {
            int u = tid + i * 256;
            int row = u >> 3, kb = u & 7;
            int4 v = *(const int4*)(A + (size_t)(m0 + row) * HDIM + k0 + kb * 8);
            *(int4*)((char*)Alds + row * 128 + ((kb ^ (row & 7)) << 4)) = v;
        }
        const int g = k0 >> 7;
        #pragma unroll
        for (int p = 0; p < 2; ++p) {
            const int ncol = (p ? IDIM : 0) + c0 + c;
            uint32_t s2u = scale_s2u(S[(size_t)g * (2 * IDIM) + ncol]);
            #pragma unroll
            for (int i = 0; i < 4; ++i) {
                int rl = rbase + i;
                uint32_t w = W[(size_t)(kt * 8 + rl) * (2 * IDIM) + ncol];
                int4 d = dec8(w, s2u);
                *(int4*)((char*)&Blds[p][0] + c * 128 + ((rl ^ (c & 7)) << 4)) = d;
            }
        }
        __syncthreads();
        #pragma unroll
        for (int ks = 0; ks < 2; ++ks) {
            f16x8 af[4], bg[4], bu[4];
            const int kb = ks * 4 + (lane >> 4);
            #pragma unroll
            for (int mi = 0; mi < 4; ++mi) {
                int m = wm * 64 + mi * 16 + (lane & 15);
                af[mi] = *(const f16x8*)((const char*)Alds + m * 128 + ((kb ^ (m & 7)) << 4));
            }
            #pragma unroll
            for (int ni = 0; ni < 4; ++ni) {
                int n = wn * 64 + ni * 16 + (lane & 15);
                bg[ni] = *(const f16x8*)((const char*)&Blds[0][0] + n * 128 + ((kb ^ (n & 7)) << 4));
                bu[ni] = *(const f16x8*)((const char*)&Blds[1][0] + n * 128 + ((kb ^ (n & 7)) << 4));
            }
            #pragma unroll
            for (int mi = 0; mi < 4; ++mi)
                #pragma unroll
                for (int ni = 0; ni < 4; ++ni) {
                    accg[mi][ni] = __builtin_amdgcn_mfma_f32_16x16x32_f16(af[mi], bg[ni], accg[mi][ni], 0, 0, 0);
                    accu[mi][ni] = __builtin_amdgcn_mfma_f32_16x16x32_f16(af[mi], bu[ni], accu[mi][ni], 0, 0, 0);
                }
        }
        __syncthreads();
    }
    #pragma unroll
    for (int mi = 0; mi < 4; ++mi) {
        #pragma unroll
        for (int ni = 0; ni < 4; ++ni) {
            int nlog = c0 + wn * 64 + ni * 16 + (lane & 15);
            int ncol = (nlog & ~7) | (((nlog & 3) << 1) | ((nlog >> 2) & 1));
            #pragma unroll
            for (int r = 0; r < 4; ++r) {
                int m = m0 + wm * 64 + mi * 16 + (lane >> 4) * 4 + r;
                float gv = accg[mi][ni][r];
                float uv = accu[mi][ni][r];
                float sig = 1.0f / (1.0f + __expf(-gv));
                act[(size_t)m * IDIM + ncol] = __float2half(gv * sig * uv);
            }
        }
    }
}

// ---------- GEMM2 (fused decode, proven ~90 us, 2D grid) ----------
__global__ __launch_bounds__(256, 2) void gemm2_add(
    const __half* __restrict__ A, const uint32_t* __restrict__ W,
    const float* __restrict__ S, const float* __restrict__ moe,
    float* __restrict__ out)
{
    __shared__ __half Alds[BM * BK];
    __shared__ __half Blds[BN * BK];
    const int tid  = threadIdx.x;
    const int lane = tid & 63;
    const int wid  = tid >> 6;
    const int wm = wid >> 1, wn = wid & 1;
    const int m0 = blockIdx.y * BM;
    const int n0 = blockIdx.x * BN;

    f32x4 acc[4][4];
    #pragma unroll
    for (int i = 0; i < 4; ++i)
        #pragma unroll
        for (int j = 0; j < 4; ++j) acc[i][j] = f32x4{0.f, 0.f, 0.f, 0.f};

    const int c = tid & 127;
    const int rbase = (tid >> 7) * 4;

    int aoff[4][2], boff[4][2];
    #pragma unroll
    for (int f = 0; f < 4; ++f)
        #pragma unroll
        for (int ks = 0; ks < 2; ++ks) {
            int kb = ks * 4 + (lane >> 4);
            int ra = wm * 64 + f * 16 + (lane & 15);
            int rb = wn * 64 + f * 16 + (lane & 15);
            aoff[f][ks] = ra * 128 + ((kb ^ (ra & 7)) << 4);
            boff[f][ks] = rb * 128 + ((kb ^ (rb & 7)) << 4);
        }

    for (int kt = 0; kt < IDIM / BK; ++kt) {
        const int k0 = kt * BK;
        #pragma unroll
        for (int i = 0; i < 4; ++i) {
            int u = tid + i * 256;
            int row = u >> 3, kb = u & 7;
            int4 v = *(const int4*)(A + (size_t)(m0 + row) * IDIM + k0 + kb * 8);
            *(int4*)((char*)Alds + row * 128 + ((kb ^ (row & 7)) << 4)) = v;
        }
        {
            const int g = k0 >> 7;
            const int ncol = n0 + c;
            uint32_t s2u = scale_s2u(S[(size_t)g * HDIM + ncol]);
            #pragma unroll
            for (int i = 0; i < 4; ++i) {
                int rl = rbase + i;
                uint32_t w = W[(size_t)(kt * 8 + rl) * HDIM + ncol];
                int4 d = dec8(w, s2u);
                *(int4*)((char*)Blds + c * 128 + ((rl ^ (c & 7)) << 4)) = d;
            }
        }
        __syncthreads();
        #pragma unroll
        for (int ks = 0; ks < 2; ++ks) {
            f16x8 af[4], bf[4];
            #pragma unroll
            for (int f = 0; f < 4; ++f) {
                af[f] = *(const f16x8*)((const char*)Alds + aoff[f][ks]);
                bf[f] = *(const f16x8*)((const char*)Blds + boff[f][ks]);
            }
            #pragma unroll
            for (int mi = 0; mi < 4; ++mi)
                #pragma unroll
                for (int ni = 0; ni < 4; ++ni)
                    acc[mi][ni] = __builtin_amdgcn_mfma_f32_16x16x32_f16(af[mi], bf[ni], acc[mi][ni], 0, 0, 0);
        }
        __syncthreads();
    }
    #pragma unroll
    for (int mi = 0; mi < 4; ++mi) {
        #pragma unroll
        for (int ni = 0; ni < 4; ++ni) {
            int n = n0 + wn * 64 + ni * 16 + (lane & 15);
            #pragma unroll
            for (int r = 0; r < 4; ++r) {
                int m = m0 + wm * 64 + mi * 16 + (lane >> 4) * 4 + r;
                out[(size_t)m * HDIM + n] = moe[(size_t)m * HDIM + n] + acc[mi][ni][r];
            }
        }
    }
}

extern "C" void kernel_launch(void* const* d_in, const int* in_sizes, int n_in,
                              void* d_out, int out_size, void* d_ws, size_t ws_size,
                              hipStream_t stream) {
    const float*    hidden = (const float*)d_in[0];
    const float*    moe    = (const float*)d_in[1];
    const uint32_t* wgu    = (const uint32_t*)d_in[2];
    const float*    sgu    = (const float*)d_in[3];
    const uint32_t* wd     = (const uint32_t*)d_in[4];
    const float*    sd     = (const float*)d_in[5];
    float* out = (float*)d_out;

    const size_t sz_hidden = (size_t)TOKENS * HDIM * 2;      // 16.78 MB
    const size_t sz_act    = (size_t)TOKENS * IDIM * 2;      // 46.14 MB
    const size_t sz_wgu16  = (size_t)HDIM * 2 * IDIM * 2;    // 46.14 MB

    __half* hidden_f16 = (__half*)d_ws;
    __half* act        = (__half*)((char*)d_ws + sz_hidden);
    __half* wgu16      = (__half*)((char*)d_ws + sz_hidden + sz_act);

    const size_t need_g1 = sz_hidden + sz_act + sz_wgu16;    // 109 MB (available r5-r11)

    convert_hidden<<<dim3(TOKENS * HDIM / 8 / 256), dim3(256), 0, stream>>>(hidden, hidden_f16);

    if (ws_size >= need_g1) {
        dequant_wgu7<<<dim3(G1_NP / 32, 32), dim3(256), 0, stream>>>(wgu, sgu, wgu16);
        gemm1_8ph2<<<dim3(G1_NP / 256, TOKENS / 256), dim3(512), 0, stream>>>(hidden_f16, wgu16, act);
    } else {
        gemm1_silu<<<dim3(IDIM / BN, TOKENS / BM), dim3(256), 0, stream>>>(hidden_f16, wgu, sgu, act);
    }

    gemm2_add<<<dim3(HDIM / BN, TOKENS / BM), dim3(256), 0, stream>>>(act, wd, sd, moe, out);
}